// Round 8
// baseline (243.811 us; speedup 1.0000x reference)
//
#include <hip/hip_runtime.h>

typedef unsigned short ushort_t;

#define M_DIM 1024   // 2*512 rows of x
#define N_DIM 4096   // OUT_F
#define K_DIM 4096   // IN_F
#define NFREQ 10000
constexpr float SCALE = 150.0f / 64.0f;   // 150 / sqrt(4096)

typedef __bf16 bf16x8_t  __attribute__((ext_vector_type(8)));
typedef float  f32x16_t  __attribute__((ext_vector_type(16)));

// Native RNE f32->bf16 (R4: measured -2us steady vs bit-twiddle RNE)
__device__ inline ushort_t f2bf(float f) {
  union { __bf16 h; ushort_t u; } v;
  v.h = (__bf16)f;
  return v.u;
}

// ---------------------------------------------------------------------------
// R8 ALGORITHM CHANGE: never build dense W' = W + iwht(scatter(...)).
//   x @ (W+DW)^T = x @ W^T  +  FWHT_row( x @ S^T ) * SCALE
// where S is the 10k-entry sparse scatter. The delta path is 10.2M MACs +
// 1024 x 4096-pt FWHT (~50M adds) -- trivial vs the 96MB W' read-mod-write
// that made build_w4 a 50us kernel. Dense part now uses bf16(plain W).
// Numerics improve: DW (the large term) is fp32-exact end-to-end.
//
// Kernel A: blocks 0..63 = entry dedup (R1-verified prep body, grouped by
// in-col group g, last-wins within (r,c)); blocks 64.. = streaming cvt of
// weight->bf16 and x->bf16.
// ---------------------------------------------------------------------------
__global__ __launch_bounds__(256) void prep_cvt(
    const float* __restrict__ weight,
    const float* __restrict__ x,
    const float* __restrict__ spectrum,
    const int* __restrict__ idx,          // [2][NFREQ]: row 0 = r (out), row 1 = c (in)
    ushort_t* __restrict__ wbb,
    ushort_t* __restrict__ xb,
    uint2* __restrict__ ent,              // [64][1024]
    int* __restrict__ cst) {              // [64][72]; [g][64] = n_g
  constexpr int CAP = 1024;
  __shared__ unsigned e_raw[CAP];
  __shared__ float    v_raw[CAP];
  __shared__ uint2    ev_srt[CAP];
  __shared__ int cnt;
  __shared__ int cstart[65];
  __shared__ int coff[64];
  __shared__ int ccnt[64];

  const int tid = threadIdx.x;

  if (blockIdx.x >= 64) {
    // ---- streaming cvt: weight (4,194,304 float4) then x (1,048,576) ----
    const int i0 = (blockIdx.x - 64) * 256 + tid;   // 2048 blocks
#pragma unroll
    for (int k = 0; k < 8; ++k) {
      int i = i0 + k * 524288;
      float4 v = ((const float4*)weight)[i];
      ushort4 o;
      o.x = f2bf(v.x); o.y = f2bf(v.y); o.z = f2bf(v.z); o.w = f2bf(v.w);
      ((ushort4*)wbb)[i] = o;
    }
#pragma unroll
    for (int k = 0; k < 2; ++k) {
      int i = i0 + k * 524288;
      float4 v = ((const float4*)x)[i];
      ushort4 o;
      o.x = f2bf(v.x); o.y = f2bf(v.y); o.z = f2bf(v.z); o.w = f2bf(v.w);
      ((ushort4*)xb)[i] = o;
    }
    return;
  }

  // ---- prep path (g = blockIdx.x): R1-verified dedup, grouped by c>>6 ----
  const int g = blockIdx.x;
  if (tid == 0) cnt = 0;
  if (tid < 64) ccnt[tid] = 0;
  __syncthreads();

  for (int j = tid; j < NFREQ; j += 256) {
    int c = idx[NFREQ + j];
    if ((c >> 6) == g) {
      int p = atomicAdd(&cnt, 1);
      if (p < CAP) {
        e_raw[p] = ((unsigned)(c & 63) << 26) | ((unsigned)j << 12) | (unsigned)idx[j];
        v_raw[p] = spectrum[j];
        atomicAdd(&ccnt[c & 63], 1);
      }
    }
  }
  __syncthreads();
  const int n = cnt < CAP ? cnt : CAP;

  if (tid < 64) {
    int v = ccnt[tid];
    int s = v;
    for (int d = 1; d < 64; d <<= 1) {
      int o = __shfl_up(s, d, 64);
      if (tid >= d) s += o;
    }
    cstart[tid + 1] = s;
    if (tid == 0) cstart[0] = 0;
    coff[tid] = s - v;   // exclusive
  }
  __syncthreads();
  for (int e = tid; e < n; e += 256) {
    unsigned w = e_raw[e];
    int dc = w >> 26;
    int p = atomicAdd(&coff[dc], 1);
    ev_srt[p] = make_uint2(w, __float_as_uint(v_raw[e]));
  }
  __syncthreads();

  // last-wins dedup within each (r, c) of this column bucket
  for (int e = tid; e < n; e += 256) {
    uint2 ev = ev_srt[e];
    int dc = ev.x >> 26;
    unsigned r = ev.x & 0xFFFu, j = (ev.x >> 12) & 0x3FFFu;
    int s0 = cstart[dc], e0 = cstart[dc + 1];
    bool dead = false;
    for (int p = s0; p < e0; ++p) {
      unsigned w2 = ev_srt[p].x;
      if ((w2 & 0xFFFu) == r && ((w2 >> 12) & 0x3FFFu) > j) dead = true;
    }
    if (dead) ev_srt[e].y = 0u;   // +0.0f: additive no-op
  }
  __syncthreads();

  for (int e = tid; e < n; e += 256) ent[g * CAP + e] = ev_srt[e];
  if (tid < 65) cst[g * 72 + tid] = cstart[tid];
}

// ---------------------------------------------------------------------------
// Kernel 2: C[M,N] = A[M,K] * B[N,K]^T  (bf16 in, fp32 out), split-K via z.
// R4-exact (best known ~47us, VGPR 60): 128x128 tile, BK=64, XOR-swizzled
// LDS, global_load_lds 16B staging, mfma_f32_32x32x16_bf16 2x2, XCD swizzle.
// B input is now bf16(plain weight).
// ---------------------------------------------------------------------------
__global__ __launch_bounds__(256) void gemm_bt(
    const ushort_t* __restrict__ A,   // xb [M,K]
    const ushort_t* __restrict__ B,   // wbb [N,K]
    float* __restrict__ C0,
    float* __restrict__ C1,
    int klen) {
  constexpr int BM = 128, BN = 128, BK = 64;
  __shared__ __align__(16) ushort_t As[BM * BK];   // 16 KB
  __shared__ __align__(16) ushort_t Bs[BN * BK];   // 16 KB

  const int tid  = threadIdx.x;
  const int wave = tid >> 6, lane = tid & 63;
  const int wrow = wave >> 1, wcol = wave & 1;
  const int l32  = lane & 31, half = lane >> 5;

  // XCD-aware swizzle (bijective on the fixed 32x8 xy-grid)
  const int fid = blockIdx.y * 32 + blockIdx.x;    // 0..255 within z-slice
  const int xcd = fid & 7, w8 = fid >> 3;
  const int sx = w8 & 7, sy = w8 >> 3;
  const int cx = xcd & 3, cy = xcd >> 2;
  const int bn = (cx * 8 + sx) * BN;
  const int bm = (cy * 4 + sy) * BM;

  const int kbeg = blockIdx.z * klen;
  float* __restrict__ dst = blockIdx.z == 0
      ? C0 : C1 + (size_t)(blockIdx.z - 1) * M_DIM * N_DIM;

  const int srow8 = lane >> 3;
  const int sq    = lane & 7;

  f32x16_t acc[2][2] = {};

  for (int kt = kbeg; kt < kbeg + klen; kt += BK) {
#pragma unroll
    for (int c = 0; c < 4; ++c) {
      int ch = wave * 4 + c;            // wave-uniform
      int gr = ch * 8 + srow8;          // tile row 0..127
      int qg = sq ^ (gr & 7);           // swizzled source quad
      const ushort_t* ga = A + (size_t)(bm + gr) * K_DIM + kt + qg * 8;
      __builtin_amdgcn_global_load_lds(
          (const __attribute__((address_space(1))) void*)ga,
          (__attribute__((address_space(3))) void*)&As[ch * 512], 16, 0, 0);
      const ushort_t* gb = B + (size_t)(bn + gr) * K_DIM + kt + qg * 8;
      __builtin_amdgcn_global_load_lds(
          (const __attribute__((address_space(1))) void*)gb,
          (__attribute__((address_space(3))) void*)&Bs[ch * 512], 16, 0, 0);
    }
    __syncthreads();

    bf16x8_t af[2][4], bfr[2][4];
#pragma unroll
    for (int mi = 0; mi < 2; ++mi) {
#pragma unroll
      for (int h = 0; h < 4; ++h) {
        int q = h * 2 + half;
        int ar = wrow * 64 + mi * 32 + l32;
        af[mi][h]  = *(const bf16x8_t*)&As[ar * BK + ((q ^ (ar & 7)) * 8)];
        int br = wcol * 64 + mi * 32 + l32;
        bfr[mi][h] = *(const bf16x8_t*)&Bs[br * BK + ((q ^ (br & 7)) * 8)];
      }
    }
#pragma unroll
    for (int h = 0; h < 4; ++h)
#pragma unroll
      for (int mi = 0; mi < 2; ++mi)
#pragma unroll
        for (int nj = 0; nj < 2; ++nj)
          acc[mi][nj] = __builtin_amdgcn_mfma_f32_32x32x16_bf16(
              af[mi][h], bfr[nj][h], acc[mi][nj], 0, 0, 0);
    __syncthreads();
  }

  // epilogue: col = lane&31, row = (reg&3) + 8*(reg>>2) + 4*half
#pragma unroll
  for (int mi = 0; mi < 2; ++mi) {
#pragma unroll
    for (int nj = 0; nj < 2; ++nj) {
      int col  = bn + wcol * 64 + nj * 32 + l32;
      int rwb  = bm + wrow * 64 + mi * 32 + 4 * half;
#pragma unroll
      for (int reg = 0; reg < 16; ++reg) {
        int row = rwb + (reg & 3) + 8 * (reg >> 2);
        dst[(size_t)row * N_DIM + col] = acc[mi][nj][reg];
      }
    }
  }
}

// ---------------------------------------------------------------------------
// Kernel 3 (R8): per-row delta + fused split-K reduce.
// Block m: G[r] = sum over deduped entries (r, i=g*64+dc, v) of v * x[m,i]
// (LDS scatter w/ atomics), then 12-stage in-LDS FWHT over r -> o, then
// out[m,o] = gemm_out + part + SCALE * D[o].
// ---------------------------------------------------------------------------
__global__ __launch_bounds__(256) void delta_fuse(
    const float* __restrict__ x,      // [1024,4096] fp32
    float* __restrict__ out,          // [1024,4096]
    const float* __restrict__ part,   // [1024,4096] (z=1 partial) or unused
    const uint2* __restrict__ ent,    // [64][1024]
    const int* __restrict__ cst,      // [64][72]
    int npart) {
  __shared__ float xrow[4096];
  __shared__ float D[4096];
  const int tid = threadIdx.x;
  const int m = blockIdx.x;

  const float* xr = x + (size_t)m * K_DIM;
#pragma unroll
  for (int i = 0; i < 4; ++i) {
    int t = tid + i * 256;
    float4 v = ((const float4*)xr)[t];
    *(float4*)&xrow[t * 4] = v;
    *(float4*)&D[t * 4] = make_float4(0.f, 0.f, 0.f, 0.f);
  }
  __syncthreads();

  // sparse scatter: D[r] += v * x[m, g*64+dc]
  for (int g = 0; g < 64; ++g) {
    const int n = cst[g * 72 + 64];
    for (int e = tid; e < n; e += 256) {
      uint2 ev = ent[g * 1024 + e];
      int dc = ev.x >> 26;
      int r  = ev.x & 0xFFFu;
      float v = __uint_as_float(ev.y);
      atomicAdd(&D[r], v * xrow[g * 64 + dc]);
    }
  }
  __syncthreads();

  // unnormalized FWHT, 12 stages (pairing partitions 0..4095 each stage)
  for (int s = 0; s < 12; ++s) {
    const int str = 1 << s;
#pragma unroll
    for (int t8 = 0; t8 < 8; ++t8) {
      int t  = tid + t8 * 256;                       // 0..2047
      int lo = (t & (str - 1)) | ((t & ~(str - 1)) << 1);
      float a = D[lo], b = D[lo + str];
      D[lo] = a + b;
      D[lo + str] = a - b;
    }
    __syncthreads();
  }

  // final: out = gemm(z0) [+ part(z1)] + SCALE * D
  float* orow = out + (size_t)m * N_DIM;
  const float* prow = part + (size_t)m * N_DIM;
#pragma unroll
  for (int i = 0; i < 4; ++i) {
    int base = (tid + i * 256) * 4;
    float4 o = *(const float4*)&orow[base];
    if (npart) {
      float4 p = *(const float4*)&prow[base];
      o.x += p.x; o.y += p.y; o.z += p.z; o.w += p.w;
    }
    o.x += SCALE * D[base + 0];
    o.y += SCALE * D[base + 1];
    o.z += SCALE * D[base + 2];
    o.w += SCALE * D[base + 3];
    *(float4*)&orow[base] = o;
  }
}

extern "C" void kernel_launch(void* const* d_in, const int* in_sizes, int n_in,
                              void* d_out, int out_size, void* d_ws, size_t ws_size,
                              hipStream_t stream) {
  const float* x        = (const float*)d_in[0];   // [2,512,4096]
  const float* weight   = (const float*)d_in[1];   // [4096,4096]
  const float* spectrum = (const float*)d_in[2];   // [10000]
  const int*   indices  = (const int*)d_in[3];     // [2,10000]
  float* out = (float*)d_out;                      // [2,512,4096]

  char* ws = (char*)d_ws;
  const size_t WB_BYTES  = (size_t)N_DIM * K_DIM * 2;          // 32 MB
  const size_t XB_BYTES  = (size_t)M_DIM * K_DIM * 2;          //  8 MB
  const size_t ENT_BYTES = (size_t)64 * 1024 * sizeof(uint2);  // 512 KB
  const size_t CST_BYTES = (size_t)64 * 72 * sizeof(int);      // 18 KB
  const size_t P1_BYTES  = (size_t)M_DIM * N_DIM * 4;          // 16 MB

  ushort_t* wbb = (ushort_t*)ws;
  ushort_t* xb  = (ushort_t*)(ws + WB_BYTES);
  uint2* ent    = (uint2*)(ws + WB_BYTES + XB_BYTES);
  int*   cst    = (int*)(ws + WB_BYTES + XB_BYTES + ENT_BYTES);
  float* part   = (float*)(ws + WB_BYTES + XB_BYTES + ENT_BYTES + CST_BYTES);

  int zsplit = (ws_size >= WB_BYTES + XB_BYTES + ENT_BYTES + CST_BYTES +
                P1_BYTES) ? 2 : 1;

  // A: dedup entries (blocks 0..63) + cvt weight/x -> bf16 (blocks 64..2111)
  prep_cvt<<<64 + 2048, 256, 0, stream>>>(weight, x, spectrum, indices,
                                          wbb, xb, ent, cst);

  // B: dense bf16 GEMM (unchanged proven kernel), split-K via z
  gemm_bt<<<dim3(N_DIM / 128, M_DIM / 128, zsplit), 256, 0, stream>>>(
      xb, wbb, out, part, K_DIM / zsplit);

  // C: sparse delta + FWHT + fused split-K reduce
  delta_fuse<<<M_DIM, 256, 0, stream>>>(x, out, part, ent, cst, zsplit - 1);
}